// Round 1
// baseline (262.019 us; speedup 1.0000x reference)
//
#include <hip/hip_runtime.h>
#include <hip/hip_bf16.h>

#define DIMSZ 256
#define HID 4096
#define BATCH 4
#define SEQ 2048
#define NCH 16      // chunks per sequence
#define CLEN 128    // chunk length (SEQ / NCH)

typedef __bf16 bf16_t;
typedef __bf16 bf16x8 __attribute__((ext_vector_type(8)));
typedef __bf16 bf16x4 __attribute__((ext_vector_type(4)));
typedef float  f32x4  __attribute__((ext_vector_type(4)));

__device__ __forceinline__ float sigmoidf_dev(float x) {
    return 1.0f / (1.0f + __expf(-x));
}

// ---------------- fp32 -> bf16 convert (vectorized x4) ----------------
__global__ void cvt_bf16_kernel(const float* __restrict__ in,
                                bf16_t* __restrict__ out, int n4) {
    int i = blockIdx.x * blockDim.x + threadIdx.x;
    if (i >= n4) return;
    float4 v = ((const float4*)in)[i];
    bf16x4 o;
    o[0] = (bf16_t)v.x; o[1] = (bf16_t)v.y;
    o[2] = (bf16_t)v.z; o[3] = (bf16_t)v.w;
    ((bf16x4*)out)[i] = o;
}

// ---------------- MFMA GEMM: C[M,N] = A[M,K] * B[N,K]^T + bias[N] ----------------
// 4 waves arranged 2x2; per-wave tile (BM/2)x(BN/2); 16x16x32 bf16 MFMA.
// A-frag: lane holds A[m=lane&15][k = (lane>>4)*8 + j], j=0..7  (8 contiguous k)
// B-frag: same layout from B^T-stored rows (n=lane&15).
// D: row = (lane>>4)*4 + reg, col = lane&15   [verified mapping, m89/m91]
template<int BM, int BN, bool OUT_BF16>
__global__ __launch_bounds__(256)
void gemm_bt(const bf16_t* __restrict__ Ag, const bf16_t* __restrict__ Bg,
             const float* __restrict__ bias, void* __restrict__ Cg,
             int M, int N, int K)
{
    constexpr int BK  = 32;
    constexpr int LDT = BK + 8;      // +8 bf16 pad -> 2-way-max bank aliasing
    constexpr int MT  = BM / 32;     // m-frags per wave
    constexpr int NT  = BN / 32;     // n-frags per wave

    __shared__ bf16_t As[BM * LDT];
    __shared__ bf16_t Bs[BN * LDT];

    const int tid  = threadIdx.x;
    const int wave = tid >> 6;
    const int lane = tid & 63;
    const int wm = wave >> 1, wn = wave & 1;
    const int q  = lane >> 4, r16 = lane & 15;
    const int mBase = blockIdx.x * BM;
    const int nBase = blockIdx.y * BN;

    f32x4 acc[MT][NT] = {};

    for (int k0 = 0; k0 < K; k0 += BK) {
        // stage A tile (BM x BK), 16B per chunk
        #pragma unroll
        for (int c = tid; c < BM * BK / 8; c += 256) {
            int row = c >> 2, col = (c & 3) << 3;
            *(bf16x8*)&As[row * LDT + col] =
                *(const bf16x8*)&Ag[(size_t)(mBase + row) * K + k0 + col];
        }
        // stage B tile (BN x BK)
        #pragma unroll
        for (int c = tid; c < BN * BK / 8; c += 256) {
            int row = c >> 2, col = (c & 3) << 3;
            *(bf16x8*)&Bs[row * LDT + col] =
                *(const bf16x8*)&Bg[(size_t)(nBase + row) * K + k0 + col];
        }
        __syncthreads();

        bf16x8 afrag[MT], bfrag[NT];
        #pragma unroll
        for (int mt = 0; mt < MT; mt++)
            afrag[mt] = *(const bf16x8*)&As[(wm * MT * 16 + mt * 16 + r16) * LDT + q * 8];
        #pragma unroll
        for (int nt = 0; nt < NT; nt++)
            bfrag[nt] = *(const bf16x8*)&Bs[(wn * NT * 16 + nt * 16 + r16) * LDT + q * 8];

        #pragma unroll
        for (int mt = 0; mt < MT; mt++)
            #pragma unroll
            for (int nt = 0; nt < NT; nt++)
                acc[mt][nt] = __builtin_amdgcn_mfma_f32_16x16x32_bf16(
                    afrag[mt], bfrag[nt], acc[mt][nt], 0, 0, 0);
        __syncthreads();
    }

    // epilogue: add bias, store
    #pragma unroll
    for (int nt = 0; nt < NT; nt++) {
        const int col = nBase + wn * NT * 16 + nt * 16 + r16;
        const float bv = bias[col];
        #pragma unroll
        for (int mt = 0; mt < MT; mt++) {
            const int row0 = mBase + wm * MT * 16 + mt * 16 + q * 4;
            #pragma unroll
            for (int rg = 0; rg < 4; rg++) {
                float v = acc[mt][nt][rg] + bv;
                size_t off = (size_t)(row0 + rg) * N + col;
                if (OUT_BF16) ((bf16_t*)Cg)[off] = (bf16_t)v;
                else          ((float*)Cg)[off]  = v;
            }
        }
    }
}

// ---------------- scan phase A: per-chunk weighted totals ----------------
// total[b][c][ch] = sum_{i=0}^{C-1} a^{C-1-i} * b_val[b, c*C+i, ch]
__global__ void scan_totals_kernel(const bf16_t* __restrict__ bv,
                                   const float* __restrict__ Adecay,
                                   float* __restrict__ totals)
{
    int gid = blockIdx.x * blockDim.x + threadIdx.x;   // BATCH*HID*NCH
    int ch    = gid & (HID - 1);
    int rest  = gid >> 12;
    int batch = rest & (BATCH - 1);
    int chunk = rest >> 2;
    float a = sigmoidf_dev(Adecay[ch]);
    size_t base = ((size_t)(batch * SEQ + chunk * CLEN)) * HID + ch;
    float tot = 0.f;
    #pragma unroll 4
    for (int i = 0; i < CLEN; i++)
        tot = a * tot + (float)bv[base + (size_t)i * HID];
    totals[(batch * NCH + chunk) * HID + ch] = tot;
}

// ---------------- scan phase B: scan over chunk carries ----------------
__global__ void scan_carries_kernel(const float* __restrict__ totals,
                                    const float* __restrict__ Adecay,
                                    float* __restrict__ carries)
{
    int gid = blockIdx.x * blockDim.x + threadIdx.x;   // BATCH*HID
    int ch    = gid & (HID - 1);
    int batch = gid >> 12;
    float a = sigmoidf_dev(Adecay[ch]);
    float aC = a;
    #pragma unroll
    for (int i = 0; i < 7; i++) aC *= aC;              // a^128
    float carry = 0.f;
    #pragma unroll
    for (int c = 0; c < NCH; c++) {
        carries[(batch * NCH + c) * HID + ch] = carry;
        carry = aC * carry + totals[(batch * NCH + c) * HID + ch];
    }
}

// ---------------- scan phase C: h_t = local_i + a^(i+1) * carry, write bf16 ----------------
__global__ void scan_write_kernel(const bf16_t* __restrict__ bv,
                                  const float* __restrict__ Adecay,
                                  const float* __restrict__ carries,
                                  bf16_t* __restrict__ h)
{
    int gid = blockIdx.x * blockDim.x + threadIdx.x;   // BATCH*HID*NCH
    int ch    = gid & (HID - 1);
    int rest  = gid >> 12;
    int batch = rest & (BATCH - 1);
    int chunk = rest >> 2;
    float a = sigmoidf_dev(Adecay[ch]);
    float carry = carries[(batch * NCH + chunk) * HID + ch];
    size_t base = ((size_t)(batch * SEQ + chunk * CLEN)) * HID + ch;
    float local = 0.f, ap = 1.f;
    #pragma unroll 4
    for (int i = 0; i < CLEN; i++) {
        local = a * local + (float)bv[base + (size_t)i * HID];
        ap *= a;
        h[base + (size_t)i * HID] = (bf16_t)(local + ap * carry);
    }
}

extern "C" void kernel_launch(void* const* d_in, const int* in_sizes, int n_in,
                              void* d_out, int out_size, void* d_ws, size_t ws_size,
                              hipStream_t stream)
{
    const float* x  = (const float*)d_in[0];   // [4,2048,256]
    const float* WB = (const float*)d_in[1];   // [4096,256]
    const float* bB = (const float*)d_in[2];   // [4096]
    const float* WC = (const float*)d_in[3];   // [256,4096]
    const float* bC = (const float*)d_in[4];   // [256]
    const float* A  = (const float*)d_in[5];   // [4096]

    char* ws = (char*)d_ws;
    size_t off = 0;
    bf16_t* xb   = (bf16_t*)(ws + off); off += (size_t)BATCH * SEQ * DIMSZ * 2; // 4 MB
    bf16_t* WBb  = (bf16_t*)(ws + off); off += (size_t)HID * DIMSZ * 2;         // 2 MB
    bf16_t* WCb  = (bf16_t*)(ws + off); off += (size_t)DIMSZ * HID * 2;         // 2 MB
    bf16_t* bbuf = (bf16_t*)(ws + off); off += (size_t)BATCH * SEQ * HID * 2;   // 64 MB
    bf16_t* hbuf = (bf16_t*)(ws + off); off += (size_t)BATCH * SEQ * HID * 2;   // 64 MB
    float* totals  = (float*)(ws + off); off += (size_t)BATCH * NCH * HID * 4;  // 1 MB
    float* carries = (float*)(ws + off); off += (size_t)BATCH * NCH * HID * 4;  // 1 MB

    const int M = BATCH * SEQ;   // 8192

    // converts
    cvt_bf16_kernel<<<(M * DIMSZ / 4 + 255) / 256, 256, 0, stream>>>(x, xb, M * DIMSZ / 4);
    cvt_bf16_kernel<<<(HID * DIMSZ / 4 + 255) / 256, 256, 0, stream>>>(WB, WBb, HID * DIMSZ / 4);
    cvt_bf16_kernel<<<(DIMSZ * HID / 4 + 255) / 256, 256, 0, stream>>>(WC, WCb, DIMSZ * HID / 4);

    // GEMM1: b = x @ WB^T + bB   -> bf16 [8192, 4096]
    dim3 g1(M / 128, HID / 128);
    gemm_bt<128, 128, true><<<g1, 256, 0, stream>>>(xb, WBb, bB, (void*)bbuf, M, HID, DIMSZ);

    // scan
    scan_totals_kernel<<<BATCH * HID * NCH / 256, 256, 0, stream>>>(bbuf, A, totals);
    scan_carries_kernel<<<BATCH * HID / 256, 256, 0, stream>>>(totals, A, carries);
    scan_write_kernel<<<BATCH * HID * NCH / 256, 256, 0, stream>>>(bbuf, A, carries, hbuf);

    // GEMM2: out = h @ WC^T + bC  -> fp32 [8192, 256]
    dim3 g2(M / 128, DIMSZ / 64);
    gemm_bt<128, 64, false><<<g2, 256, 0, stream>>>(hbuf, WCb, bC, d_out, M, DIMSZ, HID);
}

// Round 2
// 221.719 us; speedup vs baseline: 1.1818x; 1.1818x over previous
//
#include <hip/hip_runtime.h>
#include <hip/hip_bf16.h>

#define DIMSZ 256
#define HID 4096
#define BATCH 4
#define SEQ 2048
#define NCH 64      // chunks per sequence
#define CLEN 32     // chunk length (SEQ / NCH)
#define SPLITK 4    // K-splits for GEMM2

typedef __bf16 bf16_t;
typedef __bf16 bf16x8 __attribute__((ext_vector_type(8)));
typedef __bf16 bf16x4 __attribute__((ext_vector_type(4)));
typedef float  f32x4  __attribute__((ext_vector_type(4)));

__device__ __forceinline__ float sigmoidf_dev(float x) {
    return 1.0f / (1.0f + __expf(-x));
}

// ---------------- fp32 -> bf16 convert (vectorized x4) ----------------
__global__ void cvt_bf16_kernel(const float* __restrict__ in,
                                bf16_t* __restrict__ out, int n4) {
    int i = blockIdx.x * blockDim.x + threadIdx.x;
    if (i >= n4) return;
    float4 v = ((const float4*)in)[i];
    bf16x4 o;
    o[0] = (bf16_t)v.x; o[1] = (bf16_t)v.y;
    o[2] = (bf16_t)v.z; o[3] = (bf16_t)v.w;
    ((bf16x4*)out)[i] = o;
}

// ---------------- GEMM1: C[M,N] = A[M,K] * B[N,K]^T + bias[N], bf16 out ----------------
// 4 waves 2x2; 16x16x32 bf16 MFMA. D: row=(lane>>4)*4+reg, col=lane&15.
__global__ __launch_bounds__(256)
void gemm1_kernel(const bf16_t* __restrict__ Ag, const bf16_t* __restrict__ Bg,
                  const float* __restrict__ bias, bf16_t* __restrict__ Cg,
                  int M, int N, int K)
{
    constexpr int BM = 128, BN = 128, BK = 32;
    constexpr int LDT = BK + 8;
    constexpr int MT = 4, NT = 4;   // (BM/2)/16, (BN/2)/16

    __shared__ bf16_t As[BM * LDT];
    __shared__ bf16_t Bs[BN * LDT];

    const int tid  = threadIdx.x;
    const int wave = tid >> 6;
    const int lane = tid & 63;
    const int wm = wave >> 1, wn = wave & 1;
    const int q  = lane >> 4, r16 = lane & 15;
    const int mBase = blockIdx.x * BM;
    const int nBase = blockIdx.y * BN;

    f32x4 acc[MT][NT] = {};

    for (int k0 = 0; k0 < K; k0 += BK) {
        #pragma unroll
        for (int c = tid; c < BM * BK / 8; c += 256) {
            int row = c >> 2, col = (c & 3) << 3;
            *(bf16x8*)&As[row * LDT + col] =
                *(const bf16x8*)&Ag[(size_t)(mBase + row) * K + k0 + col];
        }
        #pragma unroll
        for (int c = tid; c < BN * BK / 8; c += 256) {
            int row = c >> 2, col = (c & 3) << 3;
            *(bf16x8*)&Bs[row * LDT + col] =
                *(const bf16x8*)&Bg[(size_t)(nBase + row) * K + k0 + col];
        }
        __syncthreads();

        bf16x8 afrag[MT], bfrag[NT];
        #pragma unroll
        for (int mt = 0; mt < MT; mt++)
            afrag[mt] = *(const bf16x8*)&As[(wm * 64 + mt * 16 + r16) * LDT + q * 8];
        #pragma unroll
        for (int nt = 0; nt < NT; nt++)
            bfrag[nt] = *(const bf16x8*)&Bs[(wn * 64 + nt * 16 + r16) * LDT + q * 8];

        #pragma unroll
        for (int mt = 0; mt < MT; mt++)
            #pragma unroll
            for (int nt = 0; nt < NT; nt++)
                acc[mt][nt] = __builtin_amdgcn_mfma_f32_16x16x32_bf16(
                    afrag[mt], bfrag[nt], acc[mt][nt], 0, 0, 0);
        __syncthreads();
    }

    #pragma unroll
    for (int nt = 0; nt < NT; nt++) {
        const int col = nBase + wn * 64 + nt * 16 + r16;
        const float bv = bias[col];
        #pragma unroll
        for (int mt = 0; mt < MT; mt++) {
            const int row0 = mBase + wm * 64 + mt * 16 + q * 4;
            #pragma unroll
            for (int rg = 0; rg < 4; rg++)
                Cg[(size_t)(row0 + rg) * N + col] = (bf16_t)(acc[mt][nt][rg] + bv);
        }
    }
}

// ---------------- GEMM2 split-K: P[s][M,N] = A[M, ks:ks+KC] * B[N, ks:ks+KC]^T ----------------
// BM=32, BN=256 (full N): A fetched exactly once from HBM. 4 waves across N.
__global__ __launch_bounds__(256)
void gemm_splitk(const bf16_t* __restrict__ Ag, const bf16_t* __restrict__ Bg,
                 float* __restrict__ P, int M, int N, int K)
{
    constexpr int BM = 32, BN = 256, BK = 32;
    constexpr int KCHUNK = HID / SPLITK;   // 1024
    constexpr int LDT = BK + 8;
    constexpr int MT = 2, NT = 4;          // wave tile 32x64

    __shared__ bf16_t As[BM * LDT];
    __shared__ bf16_t Bs[BN * LDT];

    const int tid  = threadIdx.x;
    const int wave = tid >> 6;
    const int lane = tid & 63;
    const int q  = lane >> 4, r16 = lane & 15;
    const int mBase = blockIdx.x * BM;
    const int kBase = blockIdx.y * KCHUNK;

    f32x4 acc[MT][NT] = {};

    for (int k0 = kBase; k0 < kBase + KCHUNK; k0 += BK) {
        if (tid < BM * BK / 8) {           // 128 chunks
            int row = tid >> 2, col = (tid & 3) << 3;
            *(bf16x8*)&As[row * LDT + col] =
                *(const bf16x8*)&Ag[(size_t)(mBase + row) * K + k0 + col];
        }
        #pragma unroll
        for (int c = tid; c < BN * BK / 8; c += 256) {
            int row = c >> 2, col = (c & 3) << 3;
            *(bf16x8*)&Bs[row * LDT + col] =
                *(const bf16x8*)&Bg[(size_t)row * K + k0 + col];
        }
        __syncthreads();

        bf16x8 afrag[MT], bfrag[NT];
        #pragma unroll
        for (int mt = 0; mt < MT; mt++)
            afrag[mt] = *(const bf16x8*)&As[(mt * 16 + r16) * LDT + q * 8];
        #pragma unroll
        for (int nt = 0; nt < NT; nt++)
            bfrag[nt] = *(const bf16x8*)&Bs[(wave * 64 + nt * 16 + r16) * LDT + q * 8];

        #pragma unroll
        for (int mt = 0; mt < MT; mt++)
            #pragma unroll
            for (int nt = 0; nt < NT; nt++)
                acc[mt][nt] = __builtin_amdgcn_mfma_f32_16x16x32_bf16(
                    afrag[mt], bfrag[nt], acc[mt][nt], 0, 0, 0);
        __syncthreads();
    }

    float* Pb = P + (size_t)blockIdx.y * M * N;
    #pragma unroll
    for (int nt = 0; nt < NT; nt++) {
        const int col = wave * 64 + nt * 16 + r16;
        #pragma unroll
        for (int mt = 0; mt < MT; mt++) {
            const int row0 = mBase + mt * 16 + q * 4;
            #pragma unroll
            for (int rg = 0; rg < 4; rg++)
                Pb[(size_t)(row0 + rg) * N + col] = acc[mt][nt][rg];
        }
    }
}

// ---------------- reduce partials + bias -> d_out ----------------
__global__ void reduce_out_kernel(const float* __restrict__ P,
                                  const float* __restrict__ bias,
                                  float* __restrict__ out, int MN4) {
    int i = blockIdx.x * blockDim.x + threadIdx.x;
    if (i >= MN4) return;
    int n4 = i & (DIMSZ / 4 - 1);
    float4 acc = ((const float4*)bias)[n4];
    #pragma unroll
    for (int s = 0; s < SPLITK; s++) {
        float4 p = ((const float4*)P)[(size_t)s * MN4 + i];
        acc.x += p.x; acc.y += p.y; acc.z += p.z; acc.w += p.w;
    }
    ((float4*)out)[i] = acc;
}

// ---------------- scan phase A: per-chunk weighted totals (x8 channels) ----------------
__global__ void scan_totals_kernel(const bf16_t* __restrict__ bv,
                                   const float* __restrict__ Adecay,
                                   float* __restrict__ totals)
{
    int gid = blockIdx.x * blockDim.x + threadIdx.x;   // BATCH*NCH*(HID/8)
    int ch0   = (gid & (HID / 8 - 1)) << 3;
    int rest  = gid >> 9;
    int chunk = rest & (NCH - 1);
    int batch = rest >> 6;

    float a[8], tot[8];
    #pragma unroll
    for (int j = 0; j < 8; j++) {
        a[j] = sigmoidf_dev(Adecay[ch0 + j]);
        tot[j] = 0.f;
    }
    size_t base = ((size_t)(batch * SEQ + chunk * CLEN)) * HID + ch0;
    #pragma unroll 8
    for (int i = 0; i < CLEN; i++) {
        bf16x8 v = *(const bf16x8*)&bv[base + (size_t)i * HID];
        #pragma unroll
        for (int j = 0; j < 8; j++) tot[j] = a[j] * tot[j] + (float)v[j];
    }
    size_t tbase = (size_t)(batch * NCH + chunk) * HID + ch0;
    #pragma unroll
    for (int j = 0; j < 8; j++) totals[tbase + j] = tot[j];
}

// ---------------- scan phase B: scan over chunk carries ----------------
__global__ void scan_carries_kernel(const float* __restrict__ totals,
                                    const float* __restrict__ Adecay,
                                    float* __restrict__ carries)
{
    int gid = blockIdx.x * blockDim.x + threadIdx.x;   // BATCH*HID
    int ch    = gid & (HID - 1);
    int batch = gid >> 12;
    float a = sigmoidf_dev(Adecay[ch]);
    float aC = a;
    #pragma unroll
    for (int i = 0; i < 5; i++) aC *= aC;              // a^32 (CLEN=32)
    float carry = 0.f;
    #pragma unroll 8
    for (int c = 0; c < NCH; c++) {
        size_t idx = (size_t)(batch * NCH + c) * HID + ch;
        carries[idx] = carry;
        carry = aC * carry + totals[idx];
    }
}

// ---------------- scan phase C: h = recurrence seeded with carry, bf16 out ----------------
__global__ void scan_write_kernel(const bf16_t* __restrict__ bv,
                                  const float* __restrict__ Adecay,
                                  const float* __restrict__ carries,
                                  bf16_t* __restrict__ h)
{
    int gid = blockIdx.x * blockDim.x + threadIdx.x;   // BATCH*NCH*(HID/8)
    int ch0   = (gid & (HID / 8 - 1)) << 3;
    int rest  = gid >> 9;
    int chunk = rest & (NCH - 1);
    int batch = rest >> 6;

    size_t cbase = (size_t)(batch * NCH + chunk) * HID + ch0;
    float a[8], st[8];
    #pragma unroll
    for (int j = 0; j < 8; j++) {
        a[j]  = sigmoidf_dev(Adecay[ch0 + j]);
        st[j] = carries[cbase + j];                    // h_{-1} = carry
    }
    size_t base = ((size_t)(batch * SEQ + chunk * CLEN)) * HID + ch0;
    #pragma unroll 8
    for (int i = 0; i < CLEN; i++) {
        bf16x8 v = *(const bf16x8*)&bv[base + (size_t)i * HID];
        bf16x8 o;
        #pragma unroll
        for (int j = 0; j < 8; j++) {
            st[j] = a[j] * st[j] + (float)v[j];
            o[j] = (bf16_t)st[j];
        }
        *(bf16x8*)&h[base + (size_t)i * HID] = o;
    }
}

extern "C" void kernel_launch(void* const* d_in, const int* in_sizes, int n_in,
                              void* d_out, int out_size, void* d_ws, size_t ws_size,
                              hipStream_t stream)
{
    const float* x  = (const float*)d_in[0];
    const float* WB = (const float*)d_in[1];
    const float* bB = (const float*)d_in[2];
    const float* WC = (const float*)d_in[3];
    const float* bC = (const float*)d_in[4];
    const float* A  = (const float*)d_in[5];

    char* ws = (char*)d_ws;
    size_t off = 0;
    bf16_t* xb   = (bf16_t*)(ws + off); off += (size_t)BATCH * SEQ * DIMSZ * 2;
    bf16_t* WBb  = (bf16_t*)(ws + off); off += (size_t)HID * DIMSZ * 2;
    bf16_t* WCb  = (bf16_t*)(ws + off); off += (size_t)DIMSZ * HID * 2;
    bf16_t* bbuf = (bf16_t*)(ws + off); off += (size_t)BATCH * SEQ * HID * 2;   // 64 MB
    bf16_t* hbuf = (bf16_t*)(ws + off); off += (size_t)BATCH * SEQ * HID * 2;   // 64 MB
    float* totals  = (float*)(ws + off); off += (size_t)BATCH * NCH * HID * 4;
    float* carries = (float*)(ws + off); off += (size_t)BATCH * NCH * HID * 4;
    // GEMM2 partials alias bbuf: bbuf is dead once scan_write finishes,
    // and SPLITK*M*N*4 = 33.5 MB < 64 MB.
    float* partials = (float*)bbuf;

    const int M = BATCH * SEQ;   // 8192

    cvt_bf16_kernel<<<(M * DIMSZ / 4 + 255) / 256, 256, 0, stream>>>(x, xb, M * DIMSZ / 4);
    cvt_bf16_kernel<<<(HID * DIMSZ / 4 + 255) / 256, 256, 0, stream>>>(WB, WBb, HID * DIMSZ / 4);
    cvt_bf16_kernel<<<(DIMSZ * HID / 4 + 255) / 256, 256, 0, stream>>>(WC, WCb, DIMSZ * HID / 4);

    // GEMM1: b = x @ WB^T + bB  -> bf16 [8192, 4096]
    dim3 g1(M / 128, HID / 128);
    gemm1_kernel<<<g1, 256, 0, stream>>>(xb, WBb, bB, bbuf, M, HID, DIMSZ);

    // scan
    int scan_threads = BATCH * NCH * (HID / 8);
    scan_totals_kernel<<<scan_threads / 256, 256, 0, stream>>>(bbuf, A, totals);
    scan_carries_kernel<<<BATCH * HID / 256, 256, 0, stream>>>(totals, A, carries);
    scan_write_kernel<<<scan_threads / 256, 256, 0, stream>>>(bbuf, A, carries, hbuf);

    // GEMM2 split-K: partials then reduce(+bias)
    dim3 g2(M / 32, SPLITK);
    gemm_splitk<<<g2, 256, 0, stream>>>(hbuf, WCb, partials, M, DIMSZ, HID);
    reduce_out_kernel<<<(M * DIMSZ / 4 + 255) / 256, 256, 0, stream>>>(
        partials, bC, (float*)d_out, M * DIMSZ / 4);
}

// Round 3
// 221.560 us; speedup vs baseline: 1.1826x; 1.0007x over previous
//
#include <hip/hip_runtime.h>
#include <hip/hip_bf16.h>

#define DIMSZ 256
#define HID 4096
#define BATCH 4
#define SEQ 2048
#define NCH 64      // chunks per sequence
#define CLEN 32     // chunk length (SEQ / NCH)
#define SPLITK 8    // K-splits for GEMM2

typedef __bf16 bf16_t;
typedef __bf16 bf16x8 __attribute__((ext_vector_type(8)));
typedef __bf16 bf16x4 __attribute__((ext_vector_type(4)));
typedef float  f32x4  __attribute__((ext_vector_type(4)));

__device__ __forceinline__ float sigmoidf_dev(float x) {
    return 1.0f / (1.0f + __expf(-x));
}

// async global->LDS, 16B per lane. LDS dest = wave-uniform base + lane*16.
__device__ __forceinline__ void load_lds16(const bf16_t* g, bf16_t* l) {
    __builtin_amdgcn_global_load_lds(
        (const __attribute__((address_space(1))) void*)g,
        (__attribute__((address_space(3))) void*)l,
        16, 0, 0);
}

// ---------------- fp32 -> bf16 convert (vectorized x4) ----------------
__global__ void cvt_bf16_kernel(const float* __restrict__ in,
                                bf16_t* __restrict__ out, int n4) {
    int i = blockIdx.x * blockDim.x + threadIdx.x;
    if (i >= n4) return;
    float4 v = ((const float4*)in)[i];
    bf16x4 o;
    o[0] = (bf16_t)v.x; o[1] = (bf16_t)v.y;
    o[2] = (bf16_t)v.z; o[3] = (bf16_t)v.w;
    ((bf16x4*)out)[i] = o;
}

// ---------------- GEMM1 fused: b = x@WB^T + bB (bf16), + per-chunk totals ----------------
// 128x128 tile, BK=32, global_load_lds staging (no LDS pad), 4 waves 2x2.
// A-frag: lane holds A[m=r16][k=q*8+j]; D: row=q*4+reg, col=r16.
// Block rows = 128 consecutive timesteps within one batch = exactly 4 chunks of CLEN=32,
// so chunk totals (sum a^{CLEN-1-i} b_i) are computed from an LDS tile in the epilogue.
__global__ __launch_bounds__(256)
void gemm1_fused(const bf16_t* __restrict__ Ag, const bf16_t* __restrict__ Bg,
                 const float* __restrict__ bias, const float* __restrict__ Adecay,
                 bf16_t* __restrict__ Cg, float* __restrict__ totals)
{
    constexpr int K = DIMSZ, N = HID;
    constexpr int LDTILE = 136;           // bf16; 272B row -> 16B aligned, spreads banks
    __shared__ bf16_t As[128 * 32];       // 8 KB
    __shared__ bf16_t Bs[128 * 32];       // 8 KB
    __shared__ bf16_t tile[128 * LDTILE]; // 34 KB

    const int tid = threadIdx.x, wave = tid >> 6, lane = tid & 63;
    const int wm = wave >> 1, wn = wave & 1, q = lane >> 4, r16 = lane & 15;
    const int mBase = blockIdx.x * 128, nBase = blockIdx.y * 128;
    const int srow = lane >> 2, scol = (lane & 3) << 3;

    f32x4 acc[4][4] = {};

    for (int k0 = 0; k0 < K; k0 += 32) {
        #pragma unroll
        for (int i = 0; i < 2; i++) {
            int c = wave * 2 + i;         // 8 chunks of 16 rows each
            load_lds16(&Ag[(size_t)(mBase + c * 16 + srow) * K + k0 + scol], &As[c * 512]);
            load_lds16(&Bg[(size_t)(nBase + c * 16 + srow) * K + k0 + scol], &Bs[c * 512]);
        }
        __syncthreads();

        bf16x8 af[4], bfr[4];
        #pragma unroll
        for (int mt = 0; mt < 4; mt++)
            af[mt] = *(const bf16x8*)&As[(wm * 64 + mt * 16 + r16) * 32 + q * 8];
        #pragma unroll
        for (int nt = 0; nt < 4; nt++)
            bfr[nt] = *(const bf16x8*)&Bs[(wn * 64 + nt * 16 + r16) * 32 + q * 8];

        #pragma unroll
        for (int mt = 0; mt < 4; mt++)
            #pragma unroll
            for (int nt = 0; nt < 4; nt++)
                acc[mt][nt] = __builtin_amdgcn_mfma_f32_16x16x32_bf16(
                    af[mt], bfr[nt], acc[mt][nt], 0, 0, 0);
        __syncthreads();
    }

    // epilogue: bias, write b to global (bf16) and to LDS tile for totals
    #pragma unroll
    for (int nt = 0; nt < 4; nt++) {
        const int chl = wn * 64 + nt * 16 + r16;
        const float bv = bias[nBase + chl];
        #pragma unroll
        for (int mt = 0; mt < 4; mt++) {
            const int t0 = wm * 64 + mt * 16 + q * 4;
            #pragma unroll
            for (int rg = 0; rg < 4; rg++) {
                bf16_t v = (bf16_t)(acc[mt][nt][rg] + bv);
                tile[(t0 + rg) * LDTILE + chl] = v;
                Cg[(size_t)(mBase + t0 + rg) * N + nBase + chl] = v;
            }
        }
    }
    __syncthreads();

    // chunk totals: 128 channels x 4 chunks = 512 tasks over 256 threads
    #pragma unroll
    for (int t = 0; t < 2; t++) {
        int task = tid + t * 256;
        int ch = task & 127, ck = task >> 7;
        float a = sigmoidf_dev(Adecay[nBase + ch]);
        float tot = 0.f;
        #pragma unroll 8
        for (int i = 0; i < CLEN; i++)
            tot = a * tot + (float)tile[(ck * CLEN + i) * LDTILE + ch];
        int batch = mBase >> 11;
        int cg = ((mBase & 2047) >> 5) + ck;
        totals[(size_t)(batch * NCH + cg) * HID + nBase + ch] = tot;
    }
}

// ---------------- GEMM2 split-K: out += h[:, ks:ks+KC] @ WC[:, ks:ks+KC]^T ----------------
// 128x128 tile (m97 shape), global_load_lds staging, fp32 atomicAdd epilogue.
__global__ __launch_bounds__(256)
void gemm2_kernel(const bf16_t* __restrict__ Ag, const bf16_t* __restrict__ Bg,
                  float* __restrict__ out)
{
    constexpr int K = HID, N = DIMSZ;
    constexpr int KCHUNK = HID / SPLITK;  // 512 -> 16 K-iters
    __shared__ bf16_t As[128 * 32];
    __shared__ bf16_t Bs[128 * 32];

    const int tid = threadIdx.x, wave = tid >> 6, lane = tid & 63;
    const int wm = wave >> 1, wn = wave & 1, q = lane >> 4, r16 = lane & 15;
    const int mBase = blockIdx.x * 128, nBase = blockIdx.y * 128;
    const int kBase = blockIdx.z * KCHUNK;
    const int srow = lane >> 2, scol = (lane & 3) << 3;

    f32x4 acc[4][4] = {};

    for (int k0 = kBase; k0 < kBase + KCHUNK; k0 += 32) {
        #pragma unroll
        for (int i = 0; i < 2; i++) {
            int c = wave * 2 + i;
            load_lds16(&Ag[(size_t)(mBase + c * 16 + srow) * K + k0 + scol], &As[c * 512]);
            load_lds16(&Bg[(size_t)(nBase + c * 16 + srow) * K + k0 + scol], &Bs[c * 512]);
        }
        __syncthreads();

        bf16x8 af[4], bfr[4];
        #pragma unroll
        for (int mt = 0; mt < 4; mt++)
            af[mt] = *(const bf16x8*)&As[(wm * 64 + mt * 16 + r16) * 32 + q * 8];
        #pragma unroll
        for (int nt = 0; nt < 4; nt++)
            bfr[nt] = *(const bf16x8*)&Bs[(wn * 64 + nt * 16 + r16) * 32 + q * 8];

        #pragma unroll
        for (int mt = 0; mt < 4; mt++)
            #pragma unroll
            for (int nt = 0; nt < 4; nt++)
                acc[mt][nt] = __builtin_amdgcn_mfma_f32_16x16x32_bf16(
                    af[mt], bfr[nt], acc[mt][nt], 0, 0, 0);
        __syncthreads();
    }

    #pragma unroll
    for (int nt = 0; nt < 4; nt++) {
        const int col = nBase + wn * 64 + nt * 16 + r16;
        #pragma unroll
        for (int mt = 0; mt < 4; mt++) {
            const int row0 = mBase + wm * 64 + mt * 16 + q * 4;
            #pragma unroll
            for (int rg = 0; rg < 4; rg++)
                atomicAdd(&out[(size_t)(row0 + rg) * N + col], acc[mt][nt][rg]);
        }
    }
}

// ---------------- init d_out with broadcast bias ----------------
__global__ void init_out_kernel(const float* __restrict__ bias,
                                float* __restrict__ out, int n4) {
    int i = blockIdx.x * blockDim.x + threadIdx.x;
    if (i >= n4) return;
    ((float4*)out)[i] = ((const float4*)bias)[i & (DIMSZ / 4 - 1)];
}

// ---------------- scan phase B: scan over chunk carries ----------------
__global__ void scan_carries_kernel(const float* __restrict__ totals,
                                    const float* __restrict__ Adecay,
                                    float* __restrict__ carries)
{
    int gid = blockIdx.x * blockDim.x + threadIdx.x;   // BATCH*HID
    int ch    = gid & (HID - 1);
    int batch = gid >> 12;
    float a = sigmoidf_dev(Adecay[ch]);
    float aC = a;
    #pragma unroll
    for (int i = 0; i < 5; i++) aC *= aC;              // a^32 (CLEN=32)
    float carry = 0.f;
    #pragma unroll 8
    for (int c = 0; c < NCH; c++) {
        size_t idx = (size_t)(batch * NCH + c) * HID + ch;
        carries[idx] = carry;
        carry = aC * carry + totals[idx];
    }
}

// ---------------- scan phase C: h = recurrence seeded with carry, bf16 out ----------------
__global__ void scan_write_kernel(const bf16_t* __restrict__ bv,
                                  const float* __restrict__ Adecay,
                                  const float* __restrict__ carries,
                                  bf16_t* __restrict__ h)
{
    int gid = blockIdx.x * blockDim.x + threadIdx.x;   // BATCH*NCH*(HID/8)
    int ch0   = (gid & (HID / 8 - 1)) << 3;
    int rest  = gid >> 9;
    int chunk = rest & (NCH - 1);
    int batch = rest >> 6;

    size_t cbase = (size_t)(batch * NCH + chunk) * HID + ch0;
    float a[8], st[8];
    #pragma unroll
    for (int j = 0; j < 8; j++) {
        a[j]  = sigmoidf_dev(Adecay[ch0 + j]);
        st[j] = carries[cbase + j];                    // h_{-1} = carry
    }
    size_t base = ((size_t)(batch * SEQ + chunk * CLEN)) * HID + ch0;
    #pragma unroll 8
    for (int i = 0; i < CLEN; i++) {
        bf16x8 v = *(const bf16x8*)&bv[base + (size_t)i * HID];
        bf16x8 o;
        #pragma unroll
        for (int j = 0; j < 8; j++) {
            st[j] = a[j] * st[j] + (float)v[j];
            o[j] = (bf16_t)st[j];
        }
        *(bf16x8*)&h[base + (size_t)i * HID] = o;
    }
}

extern "C" void kernel_launch(void* const* d_in, const int* in_sizes, int n_in,
                              void* d_out, int out_size, void* d_ws, size_t ws_size,
                              hipStream_t stream)
{
    const float* x  = (const float*)d_in[0];
    const float* WB = (const float*)d_in[1];
    const float* bB = (const float*)d_in[2];
    const float* WC = (const float*)d_in[3];
    const float* bC = (const float*)d_in[4];
    const float* A  = (const float*)d_in[5];

    char* ws = (char*)d_ws;
    size_t off = 0;
    bf16_t* xb   = (bf16_t*)(ws + off); off += (size_t)BATCH * SEQ * DIMSZ * 2;
    bf16_t* WBb  = (bf16_t*)(ws + off); off += (size_t)HID * DIMSZ * 2;
    bf16_t* WCb  = (bf16_t*)(ws + off); off += (size_t)DIMSZ * HID * 2;
    bf16_t* bbuf = (bf16_t*)(ws + off); off += (size_t)BATCH * SEQ * HID * 2;   // 64 MB
    bf16_t* hbuf = (bf16_t*)(ws + off); off += (size_t)BATCH * SEQ * HID * 2;   // 64 MB
    float* totals  = (float*)(ws + off); off += (size_t)BATCH * NCH * HID * 4;
    float* carries = (float*)(ws + off); off += (size_t)BATCH * NCH * HID * 4;

    const int M = BATCH * SEQ;   // 8192

    cvt_bf16_kernel<<<(M * DIMSZ / 4 + 255) / 256, 256, 0, stream>>>(x, xb, M * DIMSZ / 4);
    cvt_bf16_kernel<<<(HID * DIMSZ / 4 + 255) / 256, 256, 0, stream>>>(WB, WBb, HID * DIMSZ / 4);
    cvt_bf16_kernel<<<(DIMSZ * HID / 4 + 255) / 256, 256, 0, stream>>>(WC, WCb, DIMSZ * HID / 4);

    // GEMM1 fused with chunk totals
    dim3 g1(M / 128, HID / 128);
    gemm1_fused<<<g1, 256, 0, stream>>>(xb, WBb, bB, A, bbuf, totals);

    // scan
    scan_carries_kernel<<<BATCH * HID / 256, 256, 0, stream>>>(totals, A, carries);
    int scan_threads = BATCH * NCH * (HID / 8);
    scan_write_kernel<<<scan_threads / 256, 256, 0, stream>>>(bbuf, A, carries, hbuf);

    // GEMM2: init out with bias, then split-K atomic accumulate
    init_out_kernel<<<(M * DIMSZ / 4 + 255) / 256, 256, 0, stream>>>(bC, (float*)d_out, M * DIMSZ / 4);
    dim3 g2(M / 128, DIMSZ / 128, SPLITK);
    gemm2_kernel<<<g2, 256, 0, stream>>>(hbuf, WCb, (float*)d_out);
}

// Round 4
// 169.763 us; speedup vs baseline: 1.5434x; 1.3051x over previous
//
#include <hip/hip_runtime.h>
#include <hip/hip_bf16.h>

#define DIMSZ 256
#define HID 4096
#define BATCH 4
#define SEQ 2048
#define NCH 64      // chunks per sequence (carry granularity)
#define CLEN 32     // chunk length
#define SPLITK2 4   // K-splits for fused GEMM2
#define KCHUNK (HID / SPLITK2)   // 1024 channels per block
#define BM2 64      // timesteps per fused-GEMM2 block

typedef __bf16 bf16_t;
typedef __bf16 bf16x8 __attribute__((ext_vector_type(8)));
typedef __bf16 bf16x4 __attribute__((ext_vector_type(4)));
typedef float  f32x4  __attribute__((ext_vector_type(4)));

__device__ __forceinline__ float sigmoidf_dev(float x) {
    return 1.0f / (1.0f + __expf(-x));
}

// async global->LDS, 16B/lane. LDS dest = wave-uniform base + lane*16.
__device__ __forceinline__ void load_lds16(const bf16_t* g, bf16_t* l) {
    __builtin_amdgcn_global_load_lds(
        (const __attribute__((address_space(1))) void*)g,
        (__attribute__((address_space(3))) void*)l,
        16, 0, 0);
}

// ---------------- fp32 -> bf16 convert (vectorized x4) ----------------
__global__ void cvt_bf16_kernel(const float* __restrict__ in,
                                bf16_t* __restrict__ out, int n4) {
    int i = blockIdx.x * blockDim.x + threadIdx.x;
    if (i >= n4) return;
    float4 v = ((const float4*)in)[i];
    bf16x4 o;
    o[0] = (bf16_t)v.x; o[1] = (bf16_t)v.y;
    o[2] = (bf16_t)v.z; o[3] = (bf16_t)v.w;
    ((bf16x4*)out)[i] = o;
}

// ---------------- GEMM1 fused: b = x@WB^T + bB (bf16), + per-chunk totals ----------------
__global__ __launch_bounds__(256)
void gemm1_fused(const bf16_t* __restrict__ Ag, const bf16_t* __restrict__ Bg,
                 const float* __restrict__ bias, const float* __restrict__ Adecay,
                 bf16_t* __restrict__ Cg, float* __restrict__ totals)
{
    constexpr int K = DIMSZ, N = HID;
    constexpr int LDTILE = 136;
    __shared__ bf16_t As[128 * 32];
    __shared__ bf16_t Bs[128 * 32];
    __shared__ bf16_t tile[128 * LDTILE];

    const int tid = threadIdx.x, wave = tid >> 6, lane = tid & 63;
    const int wm = wave >> 1, wn = wave & 1, q = lane >> 4, r16 = lane & 15;
    const int mBase = blockIdx.x * 128, nBase = blockIdx.y * 128;
    const int srow = lane >> 2, scol = (lane & 3) << 3;

    f32x4 acc[4][4] = {};

    for (int k0 = 0; k0 < K; k0 += 32) {
        #pragma unroll
        for (int i = 0; i < 2; i++) {
            int c = wave * 2 + i;
            load_lds16(&Ag[(size_t)(mBase + c * 16 + srow) * K + k0 + scol], &As[c * 512]);
            load_lds16(&Bg[(size_t)(nBase + c * 16 + srow) * K + k0 + scol], &Bs[c * 512]);
        }
        __syncthreads();

        bf16x8 af[4], bfr[4];
        #pragma unroll
        for (int mt = 0; mt < 4; mt++)
            af[mt] = *(const bf16x8*)&As[(wm * 64 + mt * 16 + r16) * 32 + q * 8];
        #pragma unroll
        for (int nt = 0; nt < 4; nt++)
            bfr[nt] = *(const bf16x8*)&Bs[(wn * 64 + nt * 16 + r16) * 32 + q * 8];

        #pragma unroll
        for (int mt = 0; mt < 4; mt++)
            #pragma unroll
            for (int nt = 0; nt < 4; nt++)
                acc[mt][nt] = __builtin_amdgcn_mfma_f32_16x16x32_bf16(
                    af[mt], bfr[nt], acc[mt][nt], 0, 0, 0);
        __syncthreads();
    }

    #pragma unroll
    for (int nt = 0; nt < 4; nt++) {
        const int chl = wn * 64 + nt * 16 + r16;
        const float bv = bias[nBase + chl];
        #pragma unroll
        for (int mt = 0; mt < 4; mt++) {
            const int t0 = wm * 64 + mt * 16 + q * 4;
            #pragma unroll
            for (int rg = 0; rg < 4; rg++) {
                bf16_t v = (bf16_t)(acc[mt][nt][rg] + bv);
                tile[(t0 + rg) * LDTILE + chl] = v;
                Cg[(size_t)(mBase + t0 + rg) * N + nBase + chl] = v;
            }
        }
    }
    __syncthreads();

    #pragma unroll
    for (int t = 0; t < 2; t++) {
        int task = tid + t * 256;
        int ch = task & 127, ck = task >> 7;
        float a = sigmoidf_dev(Adecay[nBase + ch]);
        float tot = 0.f;
        #pragma unroll 8
        for (int i = 0; i < CLEN; i++)
            tot = a * tot + (float)tile[(ck * CLEN + i) * LDTILE + ch];
        int batch = mBase >> 11;
        int cg = ((mBase & 2047) >> 5) + ck;
        totals[(size_t)(batch * NCH + cg) * HID + nBase + ch] = tot;
    }
}

// ---------------- scan over chunk carries ----------------
__global__ void scan_carries_kernel(const float* __restrict__ totals,
                                    const float* __restrict__ Adecay,
                                    float* __restrict__ carries)
{
    int gid = blockIdx.x * blockDim.x + threadIdx.x;   // BATCH*HID
    int ch    = gid & (HID - 1);
    int batch = gid >> 12;
    float a = sigmoidf_dev(Adecay[ch]);
    float aC = a;
    #pragma unroll
    for (int i = 0; i < 5; i++) aC *= aC;              // a^32
    float carry = 0.f;
    #pragma unroll 8
    for (int c = 0; c < NCH; c++) {
        size_t idx = (size_t)(batch * NCH + c) * HID + ch;
        carries[idx] = carry;
        carry = aC * carry + totals[idx];
    }
}

// ---------------- fused scan + GEMM2 split-K ----------------
// Block: 64 timesteps (rows) x full N=256 x 1024-channel K-slice.
// Per 256-channel super-iteration: each thread owns one channel, seeds from
// the chunk carry, scans 64 steps serially, writing h into LDS in MFMA-A
// layout hs[ck][t][ch32] (row stride 64B -> conflict-free b128 reads).
// Then 8 BK=32 MFMA steps against staged WC tiles. fp32 partials out.
__global__ __launch_bounds__(256)
void gemm2_fused(const bf16_t* __restrict__ bv, const bf16_t* __restrict__ Wg,
                 const float* __restrict__ Adecay, const float* __restrict__ carries,
                 float* __restrict__ P)
{
    constexpr int N = DIMSZ;     // 256
    __shared__ bf16_t hs[8 * BM2 * 32];   // 32 KB: [ck][t][ch&31]
    __shared__ bf16_t Bs[256 * 32];       // 16 KB

    const int tid = threadIdx.x, wave = tid >> 6, lane = tid & 63;
    const int q = lane >> 4, r16 = lane & 15;
    const int mBase = blockIdx.x * BM2;
    const int kBase = blockIdx.y * KCHUNK;
    const int batch = mBase >> 11;
    const int chunk0 = (mBase & 2047) >> 5;
    const int srow = lane >> 2, scol = (lane & 3) << 3;
    const int ckOwn = tid >> 5, chOwn = tid & 31;

    f32x4 acc[4][4] = {};

    for (int s = 0; s < KCHUNK / 256; s++) {        // 4 super-iterations
        if (s > 0) __syncthreads();                  // prior MFMAs done with hs

        // ---- scan phase: channel c, 64 serial steps ----
        {
            const int c = kBase + s * 256 + tid;
            const float a = sigmoidf_dev(Adecay[c]);
            float st = carries[(size_t)(batch * NCH + chunk0) * HID + c];
            const bf16_t* bp = &bv[(size_t)mBase * HID + c];
            bf16_t* hp = &hs[ckOwn * (BM2 * 32) + chOwn];
            #pragma unroll 8
            for (int t = 0; t < BM2; t++) {
                st = a * st + (float)bp[(size_t)t * HID];
                hp[t * 32] = (bf16_t)st;
            }
        }

        // ---- MFMA phase: 8 BK=32 steps over this 256-channel slab ----
        for (int ck = 0; ck < 8; ck++) {
            __syncthreads();   // prev MFMA done with Bs (and hs writes visible at ck=0)
            // stage WC tile: 256 n-rows x 32 k  (4 passes x 4 waves x 16 rows)
            const int kcol = kBase + s * 256 + ck * 32;
            #pragma unroll
            for (int p = 0; p < 4; p++) {
                int rgrp = p * 4 + wave;             // 16-row group
                load_lds16(&Wg[(size_t)(rgrp * 16 + srow) * HID + kcol + scol],
                           &Bs[rgrp * 512]);
            }
            __syncthreads();   // Bs ready (vmcnt drained by barrier)

            bf16x8 af[4], bfr[4];
            #pragma unroll
            for (int mt = 0; mt < 4; mt++)
                af[mt] = *(const bf16x8*)&hs[ck * (BM2 * 32) + (mt * 16 + r16) * 32 + q * 8];
            #pragma unroll
            for (int nt = 0; nt < 4; nt++)
                bfr[nt] = *(const bf16x8*)&Bs[(wave * 64 + nt * 16 + r16) * 32 + q * 8];

            #pragma unroll
            for (int mt = 0; mt < 4; mt++)
                #pragma unroll
                for (int nt = 0; nt < 4; nt++)
                    acc[mt][nt] = __builtin_amdgcn_mfma_f32_16x16x32_bf16(
                        af[mt], bfr[nt], acc[mt][nt], 0, 0, 0);
        }
    }

    // ---- epilogue: fp32 partials ----
    float* Pb = P + (size_t)blockIdx.y * (BATCH * SEQ) * N;
    #pragma unroll
    for (int nt = 0; nt < 4; nt++) {
        const int col = wave * 64 + nt * 16 + r16;
        #pragma unroll
        for (int mt = 0; mt < 4; mt++) {
            const int row0 = mBase + mt * 16 + q * 4;
            #pragma unroll
            for (int rg = 0; rg < 4; rg++)
                Pb[(size_t)(row0 + rg) * N + col] = acc[mt][nt][rg];
        }
    }
}

// ---------------- reduce partials + bias -> d_out ----------------
__global__ void reduce_out_kernel(const float* __restrict__ P,
                                  const float* __restrict__ bias,
                                  float* __restrict__ out, int MN4) {
    int i = blockIdx.x * blockDim.x + threadIdx.x;
    if (i >= MN4) return;
    int n4 = i & (DIMSZ / 4 - 1);
    float4 acc = ((const float4*)bias)[n4];
    #pragma unroll
    for (int s = 0; s < SPLITK2; s++) {
        float4 p = ((const float4*)P)[(size_t)s * MN4 + i];
        acc.x += p.x; acc.y += p.y; acc.z += p.z; acc.w += p.w;
    }
    ((float4*)out)[i] = acc;
}

extern "C" void kernel_launch(void* const* d_in, const int* in_sizes, int n_in,
                              void* d_out, int out_size, void* d_ws, size_t ws_size,
                              hipStream_t stream)
{
    const float* x  = (const float*)d_in[0];
    const float* WB = (const float*)d_in[1];
    const float* bB = (const float*)d_in[2];
    const float* WC = (const float*)d_in[3];
    const float* bC = (const float*)d_in[4];
    const float* A  = (const float*)d_in[5];

    char* ws = (char*)d_ws;
    size_t off = 0;
    bf16_t* xb   = (bf16_t*)(ws + off); off += (size_t)BATCH * SEQ * DIMSZ * 2;
    bf16_t* WBb  = (bf16_t*)(ws + off); off += (size_t)HID * DIMSZ * 2;
    bf16_t* WCb  = (bf16_t*)(ws + off); off += (size_t)DIMSZ * HID * 2;
    bf16_t* bbuf = (bf16_t*)(ws + off); off += (size_t)BATCH * SEQ * HID * 2;   // 64 MB
    float* partials = (float*)(ws + off); off += (size_t)SPLITK2 * BATCH * SEQ * DIMSZ * 4; // 33.5 MB
    float* totals   = (float*)(ws + off); off += (size_t)BATCH * NCH * HID * 4;
    float* carries  = (float*)(ws + off); off += (size_t)BATCH * NCH * HID * 4;

    const int M = BATCH * SEQ;   // 8192

    cvt_bf16_kernel<<<(M * DIMSZ / 4 + 255) / 256, 256, 0, stream>>>(x, xb, M * DIMSZ / 4);
    cvt_bf16_kernel<<<(HID * DIMSZ / 4 + 255) / 256, 256, 0, stream>>>(WB, WBb, HID * DIMSZ / 4);
    cvt_bf16_kernel<<<(DIMSZ * HID / 4 + 255) / 256, 256, 0, stream>>>(WC, WCb, DIMSZ * HID / 4);

    // GEMM1 fused with chunk totals
    dim3 g1(M / 128, HID / 128);
    gemm1_fused<<<g1, 256, 0, stream>>>(xb, WBb, bB, A, bbuf, totals);

    // chunk-carry scan
    scan_carries_kernel<<<BATCH * HID / 256, 256, 0, stream>>>(totals, A, carries);

    // fused scan + GEMM2 (partials), then reduce(+bias)
    dim3 g2(M / BM2, SPLITK2);
    gemm2_fused<<<g2, 256, 0, stream>>>(bbuf, WCb, A, carries, partials);
    reduce_out_kernel<<<(M * DIMSZ / 4 + 255) / 256, 256, 0, stream>>>(
        partials, bC, (float*)d_out, M * DIMSZ / 4);
}